// Round 1
// baseline (448.171 us; speedup 1.0000x reference)
//
#include <hip/hip_runtime.h>
#include <stdint.h>

#define S_LEN 2048
#define D_MID 1024
#define N_HEADS 16
#define D_HEAD 64

typedef __attribute__((ext_vector_type(4))) float f32x4;
typedef __attribute__((ext_vector_type(8))) short bf16x8;

__device__ __forceinline__ unsigned short f2bf(float x) {
  unsigned int u = __builtin_bit_cast(unsigned int, x);
  u += 0x7fffu + ((u >> 16) & 1u);
  return (unsigned short)(u >> 16);
}
__device__ __forceinline__ unsigned int pack2(float x, float y) {
  return (unsigned int)f2bf(x) | ((unsigned int)f2bf(y) << 16);
}

#define MFMA16(a, b, c) __builtin_amdgcn_mfma_f32_16x16x32_bf16((a), (b), (c), 0, 0, 0)

// ---------------------------------------------------------------------------
// Projection GEMM: C = A(f32, MxK) * W^T(f32, NxK) + bias, output bf16.
// 128x128 tile, BK=32, 4 waves (each 64x64 via 4x4 grid of 16x16x32 MFMA).
// ---------------------------------------------------------------------------
struct ProjParams {
  const float* A[3];
  const float* W[3];
  const float* B[3];
  unsigned short* O[3];
};

__global__ __launch_bounds__(256) void gemm_proj(ProjParams P) {
  const int z = blockIdx.z;
  const float* __restrict__ A = P.A[z];
  const float* __restrict__ W = P.W[z];
  const float* __restrict__ bias = P.B[z];
  unsigned short* __restrict__ O = P.O[z];

  __shared__ __align__(16) unsigned short As[128][56];  // stride 112B: 16B-aligned, 2-way banks
  __shared__ __align__(16) unsigned short Bs[128][56];

  const int tid = threadIdx.x;
  const int lane = tid & 63, w = tid >> 6;
  const int wm = w >> 1, wn = w & 1;
  const int l15 = lane & 15, lhi = lane >> 4;
  const int m0 = blockIdx.y * 128, n0 = blockIdx.x * 128;
  const int sr = tid >> 1, sc = (tid & 1) * 16;

  f32x4 acc[4][4] = {};

  for (int k0 = 0; k0 < D_MID; k0 += 32) {
    __syncthreads();
    {
      const float* a = A + (size_t)(m0 + sr) * D_MID + k0 + sc;
      float4 a0 = ((const float4*)a)[0], a1 = ((const float4*)a)[1];
      float4 a2 = ((const float4*)a)[2], a3 = ((const float4*)a)[3];
      uint4 wa0, wa1;
      wa0.x = pack2(a0.x, a0.y); wa0.y = pack2(a0.z, a0.w);
      wa0.z = pack2(a1.x, a1.y); wa0.w = pack2(a1.z, a1.w);
      wa1.x = pack2(a2.x, a2.y); wa1.y = pack2(a2.z, a2.w);
      wa1.z = pack2(a3.x, a3.y); wa1.w = pack2(a3.z, a3.w);
      *(uint4*)&As[sr][sc] = wa0;
      *(uint4*)&As[sr][sc + 8] = wa1;

      const float* b = W + (size_t)(n0 + sr) * D_MID + k0 + sc;
      float4 b0 = ((const float4*)b)[0], b1 = ((const float4*)b)[1];
      float4 b2 = ((const float4*)b)[2], b3 = ((const float4*)b)[3];
      uint4 wb0, wb1;
      wb0.x = pack2(b0.x, b0.y); wb0.y = pack2(b0.z, b0.w);
      wb0.z = pack2(b1.x, b1.y); wb0.w = pack2(b1.z, b1.w);
      wb1.x = pack2(b2.x, b2.y); wb1.y = pack2(b2.z, b2.w);
      wb1.z = pack2(b3.x, b3.y); wb1.w = pack2(b3.z, b3.w);
      *(uint4*)&Bs[sr][sc] = wb0;
      *(uint4*)&Bs[sr][sc + 8] = wb1;
    }
    __syncthreads();

    bf16x8 af[4], bfr[4];
#pragma unroll
    for (int a = 0; a < 4; ++a)
      af[a] = *(const bf16x8*)&As[wm * 64 + a * 16 + l15][lhi * 8];
#pragma unroll
    for (int b = 0; b < 4; ++b)
      bfr[b] = *(const bf16x8*)&Bs[wn * 64 + b * 16 + l15][lhi * 8];
#pragma unroll
    for (int a = 0; a < 4; ++a)
#pragma unroll
      for (int b = 0; b < 4; ++b) acc[a][b] = MFMA16(af[a], bfr[b], acc[a][b]);
  }

#pragma unroll
  for (int a = 0; a < 4; ++a)
#pragma unroll
    for (int b = 0; b < 4; ++b) {
      const int col = n0 + wn * 64 + b * 16 + l15;
      const float bv = bias[col];
#pragma unroll
      for (int j = 0; j < 4; ++j) {
        const int row = m0 + wm * 64 + a * 16 + lhi * 4 + j;
        O[(size_t)row * D_MID + col] = f2bf(acc[a][b][j] + bv);
      }
    }
}

// ---------------------------------------------------------------------------
// Output GEMM: preLN = ctx(bf16, MxK) * wo^T(f32, NxK) + bo + Q (residual).
// ---------------------------------------------------------------------------
__global__ __launch_bounds__(256) void gemm_out(
    const unsigned short* __restrict__ Ab, const float* __restrict__ W,
    const float* __restrict__ bias, const float* __restrict__ resid,
    float* __restrict__ Of) {
  __shared__ __align__(16) unsigned short As[128][56];
  __shared__ __align__(16) unsigned short Bs[128][56];

  const int tid = threadIdx.x;
  const int lane = tid & 63, w = tid >> 6;
  const int wm = w >> 1, wn = w & 1;
  const int l15 = lane & 15, lhi = lane >> 4;
  const int m0 = blockIdx.y * 128, n0 = blockIdx.x * 128;
  const int sr = tid >> 1, sc = (tid & 1) * 16;

  f32x4 acc[4][4] = {};

  for (int k0 = 0; k0 < D_MID; k0 += 32) {
    __syncthreads();
    {
      const unsigned short* a = Ab + (size_t)(m0 + sr) * D_MID + k0 + sc;
      *(uint4*)&As[sr][sc] = *(const uint4*)a;
      *(uint4*)&As[sr][sc + 8] = *(const uint4*)(a + 8);

      const float* b = W + (size_t)(n0 + sr) * D_MID + k0 + sc;
      float4 b0 = ((const float4*)b)[0], b1 = ((const float4*)b)[1];
      float4 b2 = ((const float4*)b)[2], b3 = ((const float4*)b)[3];
      uint4 wb0, wb1;
      wb0.x = pack2(b0.x, b0.y); wb0.y = pack2(b0.z, b0.w);
      wb0.z = pack2(b1.x, b1.y); wb0.w = pack2(b1.z, b1.w);
      wb1.x = pack2(b2.x, b2.y); wb1.y = pack2(b2.z, b2.w);
      wb1.z = pack2(b3.x, b3.y); wb1.w = pack2(b3.z, b3.w);
      *(uint4*)&Bs[sr][sc] = wb0;
      *(uint4*)&Bs[sr][sc + 8] = wb1;
    }
    __syncthreads();

    bf16x8 af[4], bfr[4];
#pragma unroll
    for (int a = 0; a < 4; ++a)
      af[a] = *(const bf16x8*)&As[wm * 64 + a * 16 + l15][lhi * 8];
#pragma unroll
    for (int b = 0; b < 4; ++b)
      bfr[b] = *(const bf16x8*)&Bs[wn * 64 + b * 16 + l15][lhi * 8];
#pragma unroll
    for (int a = 0; a < 4; ++a)
#pragma unroll
      for (int b = 0; b < 4; ++b) acc[a][b] = MFMA16(af[a], bfr[b], acc[a][b]);
  }

#pragma unroll
  for (int a = 0; a < 4; ++a)
#pragma unroll
    for (int b = 0; b < 4; ++b) {
      const int col = n0 + wn * 64 + b * 16 + l15;
      const float bv = bias[col];
#pragma unroll
      for (int j = 0; j < 4; ++j) {
        const int row = m0 + wm * 64 + a * 16 + lhi * 4 + j;
        Of[(size_t)row * D_MID + col] =
            acc[a][b][j] + bv + resid[(size_t)row * D_MID + col];
      }
    }
}

// ---------------------------------------------------------------------------
// bf16 transpose: v[2048][1024] -> vt[1024][2048] (64x64 tiles via LDS)
// ---------------------------------------------------------------------------
__global__ __launch_bounds__(256) void transpose_to_vbt(
    const unsigned short* __restrict__ v, unsigned short* __restrict__ vt) {
  __shared__ __align__(16) unsigned short t[64][72];
  const int tid = threadIdx.x;
  const int bs = blockIdx.x * 64;  // seq block
  const int bd = blockIdx.y * 64;  // dim block
  {
    const int r = tid >> 2, c = (tid & 3) * 16;
    const unsigned short* src = v + (size_t)(bs + r) * D_MID + bd + c;
    *(uint4*)&t[r][c] = *(const uint4*)src;
    *(uint4*)&t[r][c + 8] = *(const uint4*)(src + 8);
  }
  __syncthreads();
  {
    const int d = tid >> 2, c = (tid & 3) * 16;
    unsigned int u[8];
#pragma unroll
    for (int jj = 0; jj < 8; ++jj)
      u[jj] = (unsigned int)t[c + 2 * jj][d] | ((unsigned int)t[c + 2 * jj + 1][d] << 16);
    uint4 w0, w1;
    w0.x = u[0]; w0.y = u[1]; w0.z = u[2]; w0.w = u[3];
    w1.x = u[4]; w1.y = u[5]; w1.z = u[6]; w1.w = u[7];
    unsigned short* dst = vt + (size_t)(bd + d) * S_LEN + bs + c;
    *(uint4*)dst = w0;
    *(uint4*)(dst + 8) = w1;
  }
}

// ---------------------------------------------------------------------------
// Attention: one block = (head, 64 q rows), 4 waves x 16 q rows each.
// Two passes over K/V tiles of 64: pass1 row max/sum, pass2 write attn + PV.
// ---------------------------------------------------------------------------
__global__ __launch_bounds__(256) void attn_kernel(
    const unsigned short* __restrict__ qb, const unsigned short* __restrict__ kb,
    const unsigned short* __restrict__ vbt, const void* __restrict__ maskp,
    float* __restrict__ attn_out, float* __restrict__ ctx2_out,
    unsigned short* __restrict__ ctxb) {
  const int head = blockIdx.x;
  const int q0 = blockIdx.y * 64;
  const int tid = threadIdx.x;
  const int lane = tid & 63, w = tid >> 6;
  const int l15 = lane & 15, lhi = lane >> 4;

  __shared__ __align__(16) unsigned short Kt[64][72];  // [key][dk]
  __shared__ __align__(16) unsigned short Vt[64][72];  // [d][key]
  __shared__ __align__(16) unsigned short Pl[4][16][72];  // per-wave P relayout
  __shared__ int s_m32;

  // --- mask dtype detection: int32 has zero bytes at i%4!=0 ---
  if (tid == 0) s_m32 = 1;
  __syncthreads();
  {
    const unsigned char* m8d = (const unsigned char*)maskp;
    bool nz = false;
    for (int i = tid; i < 4096; i += 256)
      if (i & 3) nz |= (m8d[i] != 0);
    if (nz) s_m32 = 0;  // benign race: all writers store 0
  }
  __syncthreads();
  const int m32 = s_m32;
  const unsigned char* m8 = (const unsigned char*)maskp;
  const int* mi = (const int*)maskp;

  // Q fragments (A operand): rows = q, 2 k-chunks of 32
  bf16x8 aq[2];
  {
    const unsigned short* qp =
        qb + (size_t)(q0 + w * 16 + l15) * D_MID + head * D_HEAD + lhi * 8;
    aq[0] = *(const bf16x8*)qp;
    aq[1] = *(const bf16x8*)(qp + 32);
  }

  float mrow[4] = {-INFINITY, -INFINITY, -INFINITY, -INFINITY};
  float lrow[4] = {0.f, 0.f, 0.f, 0.f};

  const int sk = tid >> 2, sc = (tid & 3) * 16;

  // ---- pass 1: running max & sum ----
  for (int kt = 0; kt < S_LEN; kt += 64) {
    __syncthreads();
    {
      const unsigned short* src = kb + (size_t)(kt + sk) * D_MID + head * D_HEAD + sc;
      *(uint4*)&Kt[sk][sc] = *(const uint4*)src;
      *(uint4*)&Kt[sk][sc + 8] = *(const uint4*)(src + 8);
    }
    __syncthreads();

    f32x4 sacc[4];
#pragma unroll
    for (int a = 0; a < 4; ++a) {
      bf16x8 b0 = *(const bf16x8*)&Kt[a * 16 + l15][lhi * 8];
      bf16x8 b1 = *(const bf16x8*)&Kt[a * 16 + l15][32 + lhi * 8];
      f32x4 t = {0.f, 0.f, 0.f, 0.f};
      t = MFMA16(aq[0], b0, t);
      t = MFMA16(aq[1], b1, t);
      sacc[a] = t;
    }

#pragma unroll
    for (int j = 0; j < 4; ++j) {
      const int qg = q0 + w * 16 + lhi * 4 + j;
      float sv[4];
      float tmax = -INFINITY;
#pragma unroll
      for (int a = 0; a < 4; ++a) {
        const int kg = kt + a * 16 + l15;
        const bool mk = m32 ? (mi[(size_t)qg * S_LEN + kg] != 0)
                            : (m8[(size_t)qg * S_LEN + kg] != 0);
        const float s = mk ? -INFINITY : sacc[a][j] * 0.125f;
        sv[a] = s;
        tmax = fmaxf(tmax, s);
      }
#pragma unroll
      for (int off = 1; off < 16; off <<= 1)
        tmax = fmaxf(tmax, __shfl_xor(tmax, off));
      const float mn = fmaxf(mrow[j], tmax);
      if (mn > -INFINITY) {
        float ts = 0.f;
#pragma unroll
        for (int a = 0; a < 4; ++a) ts += __expf(sv[a] - mn);  // exp(-inf)=0
#pragma unroll
        for (int off = 1; off < 16; off <<= 1) ts += __shfl_xor(ts, off);
        const float corr = (mrow[j] == -INFINITY) ? 0.f : __expf(mrow[j] - mn);
        lrow[j] = lrow[j] * corr + ts;
        mrow[j] = mn;
      }
    }
  }

  float linv[4];
#pragma unroll
  for (int j = 0; j < 4; ++j) linv[j] = (lrow[j] > 0.f) ? 1.f / lrow[j] : 0.f;

  f32x4 cacc[4] = {};

  // ---- pass 2: write normalized attn + accumulate ctx ----
  for (int kt = 0; kt < S_LEN; kt += 64) {
    __syncthreads();
    {
      const unsigned short* srck = kb + (size_t)(kt + sk) * D_MID + head * D_HEAD + sc;
      *(uint4*)&Kt[sk][sc] = *(const uint4*)srck;
      *(uint4*)&Kt[sk][sc + 8] = *(const uint4*)(srck + 8);
      const unsigned short* srcv = vbt + (size_t)(head * D_HEAD + sk) * S_LEN + kt + sc;
      *(uint4*)&Vt[sk][sc] = *(const uint4*)srcv;
      *(uint4*)&Vt[sk][sc + 8] = *(const uint4*)(srcv + 8);
    }
    __syncthreads();

    f32x4 sacc[4];
#pragma unroll
    for (int a = 0; a < 4; ++a) {
      bf16x8 b0 = *(const bf16x8*)&Kt[a * 16 + l15][lhi * 8];
      bf16x8 b1 = *(const bf16x8*)&Kt[a * 16 + l15][32 + lhi * 8];
      f32x4 t = {0.f, 0.f, 0.f, 0.f};
      t = MFMA16(aq[0], b0, t);
      t = MFMA16(aq[1], b1, t);
      sacc[a] = t;
    }

#pragma unroll
    for (int j = 0; j < 4; ++j) {
      const int qg = q0 + w * 16 + lhi * 4 + j;
#pragma unroll
      for (int a = 0; a < 4; ++a) {
        const int kg = kt + a * 16 + l15;
        const bool mk = m32 ? (mi[(size_t)qg * S_LEN + kg] != 0)
                            : (m8[(size_t)qg * S_LEN + kg] != 0);
        float p = 0.f;
        if (!mk && mrow[j] > -INFINITY)
          p = __expf(sacc[a][j] * 0.125f - mrow[j]) * linv[j];
        attn_out[(size_t)head * S_LEN * S_LEN + (size_t)qg * S_LEN + kg] = p;
        Pl[w][lhi * 4 + j][a * 16 + l15] = f2bf(p);
      }
    }

    // wave-local LDS roundtrip: C-layout -> A-fragment layout (in-order DS pipe)
    bf16x8 pa0 = *(const bf16x8*)&Pl[w][l15][lhi * 8];
    bf16x8 pa1 = *(const bf16x8*)&Pl[w][l15][32 + lhi * 8];
#pragma unroll
    for (int n = 0; n < 4; ++n) {
      bf16x8 v0 = *(const bf16x8*)&Vt[n * 16 + l15][lhi * 8];
      bf16x8 v1 = *(const bf16x8*)&Vt[n * 16 + l15][32 + lhi * 8];
      cacc[n] = MFMA16(pa0, v0, cacc[n]);
      cacc[n] = MFMA16(pa1, v1, cacc[n]);
    }
  }

#pragma unroll
  for (int n = 0; n < 4; ++n)
#pragma unroll
    for (int j = 0; j < 4; ++j) {
      const int qg = q0 + w * 16 + lhi * 4 + j;
      const int col = head * D_HEAD + n * 16 + l15;
      const float cv = cacc[n][j];
      ctx2_out[(size_t)qg * D_MID + col] = cv;
      ctxb[(size_t)qg * D_MID + col] = f2bf(cv);
    }
}

// ---------------------------------------------------------------------------
// Row LayerNorm: 1 block per row of 1024
// ---------------------------------------------------------------------------
__global__ __launch_bounds__(256) void layernorm_k(
    const float* __restrict__ x, const float* __restrict__ gamma,
    const float* __restrict__ beta, float* __restrict__ out) {
  const int row = blockIdx.x;
  const int tid = threadIdx.x;
  float4 v = ((const float4*)(x + (size_t)row * D_MID))[tid];
  float s = v.x + v.y + v.z + v.w;
  float s2 = v.x * v.x + v.y * v.y + v.z * v.z + v.w * v.w;
#pragma unroll
  for (int off = 1; off < 64; off <<= 1) {
    s += __shfl_xor(s, off);
    s2 += __shfl_xor(s2, off);
  }
  __shared__ float ps[4], ps2[4];
  const int w = tid >> 6;
  if ((tid & 63) == 0) { ps[w] = s; ps2[w] = s2; }
  __syncthreads();
  s = ps[0] + ps[1] + ps[2] + ps[3];
  s2 = ps2[0] + ps2[1] + ps2[2] + ps2[3];
  const float mu = s * (1.0f / D_MID);
  const float var = s2 * (1.0f / D_MID) - mu * mu;
  const float inv = rsqrtf(var + 1e-5f);
  float4 g = ((const float4*)gamma)[tid];
  float4 b = ((const float4*)beta)[tid];
  float4 o;
  o.x = (v.x - mu) * inv * g.x + b.x;
  o.y = (v.y - mu) * inv * g.y + b.y;
  o.z = (v.z - mu) * inv * g.z + b.z;
  o.w = (v.w - mu) * inv * g.w + b.w;
  ((float4*)(out + (size_t)row * D_MID))[tid] = o;
}

// ---------------------------------------------------------------------------
extern "C" void kernel_launch(void* const* d_in, const int* in_sizes, int n_in,
                              void* d_out, int out_size, void* d_ws, size_t ws_size,
                              hipStream_t stream) {
  (void)in_sizes; (void)n_in; (void)out_size;
  const float* Q = (const float*)d_in[0];
  const float* K = (const float*)d_in[1];
  const float* V = (const float*)d_in[2];
  const void* mask = d_in[3];
  const float* wq = (const float*)d_in[4];
  const float* bq = (const float*)d_in[5];
  const float* wk = (const float*)d_in[6];
  const float* bk = (const float*)d_in[7];
  const float* wv = (const float*)d_in[8];
  const float* bv = (const float*)d_in[9];
  const float* wo = (const float*)d_in[10];
  const float* bo = (const float*)d_in[11];
  const float* gamma = (const float*)d_in[12];
  const float* beta = (const float*)d_in[13];

  float* out = (float*)d_out;                       // (1,2048,1024)
  float* attn = out + (size_t)S_LEN * D_MID;        // (1,16,2048,2048)
  float* ctx2 = attn + (size_t)N_HEADS * S_LEN * S_LEN;  // (2048,1,1024)

  unsigned char* ws = (unsigned char*)d_ws;         // needs 28 MB
  unsigned short* qb = (unsigned short*)(ws);
  unsigned short* kbuf = (unsigned short*)(ws + (size_t)(4 << 20));
  unsigned short* vbuf = (unsigned short*)(ws + (size_t)(8 << 20));
  unsigned short* vbt = (unsigned short*)(ws + (size_t)(12 << 20));
  unsigned short* ctxb = (unsigned short*)(ws + (size_t)(16 << 20));
  float* preLN = (float*)(ws + (size_t)(20 << 20));

  ProjParams pp;
  pp.A[0] = Q;  pp.W[0] = wq; pp.B[0] = bq; pp.O[0] = qb;
  pp.A[1] = K;  pp.W[1] = wk; pp.B[1] = bk; pp.O[1] = kbuf;
  pp.A[2] = V;  pp.W[2] = wv; pp.B[2] = bv; pp.O[2] = vbuf;

  gemm_proj<<<dim3(D_MID / 128, S_LEN / 128, 3), 256, 0, stream>>>(pp);
  transpose_to_vbt<<<dim3(S_LEN / 64, D_MID / 64), 256, 0, stream>>>(vbuf, vbt);
  attn_kernel<<<dim3(N_HEADS, S_LEN / 64), 256, 0, stream>>>(
      qb, kbuf, vbt, mask, attn, ctx2, ctxb);
  gemm_out<<<dim3(D_MID / 128, S_LEN / 128), 256, 0, stream>>>(
      ctxb, wo, bo, Q, preLN);
  layernorm_k<<<S_LEN, 256, 0, stream>>>(preLN, gamma, beta, out);
}

// Round 2
// 440.399 us; speedup vs baseline: 1.0176x; 1.0176x over previous
//
#include <hip/hip_runtime.h>
#include <stdint.h>

#define S_LEN 2048
#define D_MID 1024
#define N_HEADS 16
#define D_HEAD 64

typedef __attribute__((ext_vector_type(4))) float f32x4;
typedef __attribute__((ext_vector_type(8))) short bf16x8;

__device__ __forceinline__ unsigned short f2bf(float x) {
  unsigned int u = __builtin_bit_cast(unsigned int, x);
  u += 0x7fffu + ((u >> 16) & 1u);
  return (unsigned short)(u >> 16);
}
__device__ __forceinline__ unsigned int pack2(float x, float y) {
  return (unsigned int)f2bf(x) | ((unsigned int)f2bf(y) << 16);
}

#define MFMA16(a, b, c) __builtin_amdgcn_mfma_f32_16x16x32_bf16((a), (b), (c), 0, 0, 0)

// ---------------------------------------------------------------------------
// Projection GEMM: C = A(f32, MxK) * W^T(f32, NxK) + bias, output bf16.
// 128x128 tile, BK=32, 4 waves (each 64x64 via 4x4 grid of 16x16x32 MFMA).
// ---------------------------------------------------------------------------
struct ProjParams {
  const float* A[3];
  const float* W[3];
  const float* B[3];
  unsigned short* O[3];
};

__global__ __launch_bounds__(256) void gemm_proj(ProjParams P) {
  const int z = blockIdx.z;
  const float* __restrict__ A = P.A[z];
  const float* __restrict__ W = P.W[z];
  const float* __restrict__ bias = P.B[z];
  unsigned short* __restrict__ O = P.O[z];

  __shared__ __align__(16) unsigned short As[128][56];  // stride 112B: 16B-aligned, 2-way banks
  __shared__ __align__(16) unsigned short Bs[128][56];

  const int tid = threadIdx.x;
  const int lane = tid & 63, w = tid >> 6;
  const int wm = w >> 1, wn = w & 1;
  const int l15 = lane & 15, lhi = lane >> 4;
  const int m0 = blockIdx.y * 128, n0 = blockIdx.x * 128;
  const int sr = tid >> 1, sc = (tid & 1) * 16;

  f32x4 acc[4][4] = {};

  for (int k0 = 0; k0 < D_MID; k0 += 32) {
    __syncthreads();
    {
      const float* a = A + (size_t)(m0 + sr) * D_MID + k0 + sc;
      float4 a0 = ((const float4*)a)[0], a1 = ((const float4*)a)[1];
      float4 a2 = ((const float4*)a)[2], a3 = ((const float4*)a)[3];
      uint4 wa0, wa1;
      wa0.x = pack2(a0.x, a0.y); wa0.y = pack2(a0.z, a0.w);
      wa0.z = pack2(a1.x, a1.y); wa0.w = pack2(a1.z, a1.w);
      wa1.x = pack2(a2.x, a2.y); wa1.y = pack2(a2.z, a2.w);
      wa1.z = pack2(a3.x, a3.y); wa1.w = pack2(a3.z, a3.w);
      *(uint4*)&As[sr][sc] = wa0;
      *(uint4*)&As[sr][sc + 8] = wa1;

      const float* b = W + (size_t)(n0 + sr) * D_MID + k0 + sc;
      float4 b0 = ((const float4*)b)[0], b1 = ((const float4*)b)[1];
      float4 b2 = ((const float4*)b)[2], b3 = ((const float4*)b)[3];
      uint4 wb0, wb1;
      wb0.x = pack2(b0.x, b0.y); wb0.y = pack2(b0.z, b0.w);
      wb0.z = pack2(b1.x, b1.y); wb0.w = pack2(b1.z, b1.w);
      wb1.x = pack2(b2.x, b2.y); wb1.y = pack2(b2.z, b2.w);
      wb1.z = pack2(b3.x, b3.y); wb1.w = pack2(b3.z, b3.w);
      *(uint4*)&Bs[sr][sc] = wb0;
      *(uint4*)&Bs[sr][sc + 8] = wb1;
    }
    __syncthreads();

    bf16x8 af[4], bfr[4];
#pragma unroll
    for (int a = 0; a < 4; ++a)
      af[a] = *(const bf16x8*)&As[wm * 64 + a * 16 + l15][lhi * 8];
#pragma unroll
    for (int b = 0; b < 4; ++b)
      bfr[b] = *(const bf16x8*)&Bs[wn * 64 + b * 16 + l15][lhi * 8];
#pragma unroll
    for (int a = 0; a < 4; ++a)
#pragma unroll
      for (int b = 0; b < 4; ++b) acc[a][b] = MFMA16(af[a], bfr[b], acc[a][b]);
  }

#pragma unroll
  for (int a = 0; a < 4; ++a)
#pragma unroll
    for (int b = 0; b < 4; ++b) {
      const int col = n0 + wn * 64 + b * 16 + l15;
      const float bv = bias[col];
#pragma unroll
      for (int j = 0; j < 4; ++j) {
        const int row = m0 + wm * 64 + a * 16 + lhi * 4 + j;
        O[(size_t)row * D_MID + col] = f2bf(acc[a][b][j] + bv);
      }
    }
}

// ---------------------------------------------------------------------------
// Output GEMM: preLN = ctx(bf16, MxK) * wo^T(f32, NxK) + bo + Q (residual).
// ---------------------------------------------------------------------------
__global__ __launch_bounds__(256) void gemm_out(
    const unsigned short* __restrict__ Ab, const float* __restrict__ W,
    const float* __restrict__ bias, const float* __restrict__ resid,
    float* __restrict__ Of) {
  __shared__ __align__(16) unsigned short As[128][56];
  __shared__ __align__(16) unsigned short Bs[128][56];

  const int tid = threadIdx.x;
  const int lane = tid & 63, w = tid >> 6;
  const int wm = w >> 1, wn = w & 1;
  const int l15 = lane & 15, lhi = lane >> 4;
  const int m0 = blockIdx.y * 128, n0 = blockIdx.x * 128;
  const int sr = tid >> 1, sc = (tid & 1) * 16;

  f32x4 acc[4][4] = {};

  for (int k0 = 0; k0 < D_MID; k0 += 32) {
    __syncthreads();
    {
      const unsigned short* a = Ab + (size_t)(m0 + sr) * D_MID + k0 + sc;
      *(uint4*)&As[sr][sc] = *(const uint4*)a;
      *(uint4*)&As[sr][sc + 8] = *(const uint4*)(a + 8);

      const float* b = W + (size_t)(n0 + sr) * D_MID + k0 + sc;
      float4 b0 = ((const float4*)b)[0], b1 = ((const float4*)b)[1];
      float4 b2 = ((const float4*)b)[2], b3 = ((const float4*)b)[3];
      uint4 wb0, wb1;
      wb0.x = pack2(b0.x, b0.y); wb0.y = pack2(b0.z, b0.w);
      wb0.z = pack2(b1.x, b1.y); wb0.w = pack2(b1.z, b1.w);
      wb1.x = pack2(b2.x, b2.y); wb1.y = pack2(b2.z, b2.w);
      wb1.z = pack2(b3.x, b3.y); wb1.w = pack2(b3.z, b3.w);
      *(uint4*)&Bs[sr][sc] = wb0;
      *(uint4*)&Bs[sr][sc + 8] = wb1;
    }
    __syncthreads();

    bf16x8 af[4], bfr[4];
#pragma unroll
    for (int a = 0; a < 4; ++a)
      af[a] = *(const bf16x8*)&As[wm * 64 + a * 16 + l15][lhi * 8];
#pragma unroll
    for (int b = 0; b < 4; ++b)
      bfr[b] = *(const bf16x8*)&Bs[wn * 64 + b * 16 + l15][lhi * 8];
#pragma unroll
    for (int a = 0; a < 4; ++a)
#pragma unroll
      for (int b = 0; b < 4; ++b) acc[a][b] = MFMA16(af[a], bfr[b], acc[a][b]);
  }

#pragma unroll
  for (int a = 0; a < 4; ++a)
#pragma unroll
    for (int b = 0; b < 4; ++b) {
      const int col = n0 + wn * 64 + b * 16 + l15;
      const float bv = bias[col];
#pragma unroll
      for (int j = 0; j < 4; ++j) {
        const int row = m0 + wm * 64 + a * 16 + lhi * 4 + j;
        Of[(size_t)row * D_MID + col] =
            acc[a][b][j] + bv + resid[(size_t)row * D_MID + col];
      }
    }
}

// ---------------------------------------------------------------------------
// bf16 transpose: v[2048][1024] -> vt[1024][2048] (64x64 tiles via LDS)
// ---------------------------------------------------------------------------
__global__ __launch_bounds__(256) void transpose_to_vbt(
    const unsigned short* __restrict__ v, unsigned short* __restrict__ vt) {
  __shared__ __align__(16) unsigned short t[64][72];
  const int tid = threadIdx.x;
  const int bs = blockIdx.x * 64;  // seq block
  const int bd = blockIdx.y * 64;  // dim block
  {
    const int r = tid >> 2, c = (tid & 3) * 16;
    const unsigned short* src = v + (size_t)(bs + r) * D_MID + bd + c;
    *(uint4*)&t[r][c] = *(const uint4*)src;
    *(uint4*)&t[r][c + 8] = *(const uint4*)(src + 8);
  }
  __syncthreads();
  {
    const int d = tid >> 2, c = (tid & 3) * 16;
    unsigned int u[8];
#pragma unroll
    for (int jj = 0; jj < 8; ++jj)
      u[jj] = (unsigned int)t[c + 2 * jj][d] | ((unsigned int)t[c + 2 * jj + 1][d] << 16);
    uint4 w0, w1;
    w0.x = u[0]; w0.y = u[1]; w0.z = u[2]; w0.w = u[3];
    w1.x = u[4]; w1.y = u[5]; w1.z = u[6]; w1.w = u[7];
    unsigned short* dst = vt + (size_t)(bd + d) * S_LEN + bs + c;
    *(uint4*)dst = w0;
    *(uint4*)(dst + 8) = w1;
  }
}

// ---------------------------------------------------------------------------
// Attention: one block = (head, 64 q rows), 4 waves x 16 q rows each.
// Two passes over K/V tiles of 64: pass1 row max/sum, pass2 write attn + PV.
// ---------------------------------------------------------------------------
__global__ __launch_bounds__(256) void attn_kernel(
    const unsigned short* __restrict__ qb, const unsigned short* __restrict__ kb,
    const unsigned short* __restrict__ vbt, const void* __restrict__ maskp,
    float* __restrict__ attn_out, float* __restrict__ ctx2_out,
    unsigned short* __restrict__ ctxb) {
  const int head = blockIdx.x;
  const int q0 = blockIdx.y * 64;
  const int tid = threadIdx.x;
  const int lane = tid & 63, w = tid >> 6;
  const int l15 = lane & 15, lhi = lane >> 4;

  __shared__ __align__(16) unsigned short Kt[64][72];  // [key][dk]
  __shared__ __align__(16) unsigned short Vt[64][72];  // [d][key]
  __shared__ __align__(16) unsigned short Pl[4][16][72];  // per-wave P relayout
  __shared__ int s_m32;

  // --- mask dtype detection: int32 has zero bytes at i%4!=0 ---
  if (tid == 0) s_m32 = 1;
  __syncthreads();
  {
    const unsigned char* m8d = (const unsigned char*)maskp;
    bool nz = false;
    for (int i = tid; i < 4096; i += 256)
      if (i & 3) nz |= (m8d[i] != 0);
    if (nz) s_m32 = 0;  // benign race: all writers store 0
  }
  __syncthreads();
  const int m32 = s_m32;
  const unsigned char* m8 = (const unsigned char*)maskp;
  const int* mi = (const int*)maskp;

  // Q fragments (A operand): rows = q, 2 k-chunks of 32
  bf16x8 aq[2];
  {
    const unsigned short* qp =
        qb + (size_t)(q0 + w * 16 + l15) * D_MID + head * D_HEAD + lhi * 8;
    aq[0] = *(const bf16x8*)qp;
    aq[1] = *(const bf16x8*)(qp + 32);
  }

  float mrow[4] = {-INFINITY, -INFINITY, -INFINITY, -INFINITY};
  float lrow[4] = {0.f, 0.f, 0.f, 0.f};

  const int sk = tid >> 2, sc = (tid & 3) * 16;

  // ---- pass 1: running max & sum ----
  for (int kt = 0; kt < S_LEN; kt += 64) {
    __syncthreads();
    {
      const unsigned short* src = kb + (size_t)(kt + sk) * D_MID + head * D_HEAD + sc;
      *(uint4*)&Kt[sk][sc] = *(const uint4*)src;
      *(uint4*)&Kt[sk][sc + 8] = *(const uint4*)(src + 8);
    }
    __syncthreads();

    f32x4 sacc[4];
#pragma unroll
    for (int a = 0; a < 4; ++a) {
      bf16x8 b0 = *(const bf16x8*)&Kt[a * 16 + l15][lhi * 8];
      bf16x8 b1 = *(const bf16x8*)&Kt[a * 16 + l15][32 + lhi * 8];
      f32x4 t = {0.f, 0.f, 0.f, 0.f};
      t = MFMA16(aq[0], b0, t);
      t = MFMA16(aq[1], b1, t);
      sacc[a] = t;
    }

#pragma unroll
    for (int j = 0; j < 4; ++j) {
      const int qg = q0 + w * 16 + lhi * 4 + j;
      float sv[4];
      float tmax = -INFINITY;
#pragma unroll
      for (int a = 0; a < 4; ++a) {
        const int kg = kt + a * 16 + l15;
        const bool mk = m32 ? (mi[(size_t)qg * S_LEN + kg] != 0)
                            : (m8[(size_t)qg * S_LEN + kg] != 0);
        const float s = mk ? -INFINITY : sacc[a][j] * 0.125f;
        sv[a] = s;
        tmax = fmaxf(tmax, s);
      }
#pragma unroll
      for (int off = 1; off < 16; off <<= 1)
        tmax = fmaxf(tmax, __shfl_xor(tmax, off));
      const float mn = fmaxf(mrow[j], tmax);
      if (mn > -INFINITY) {
        float ts = 0.f;
#pragma unroll
        for (int a = 0; a < 4; ++a) ts += __expf(sv[a] - mn);  // exp(-inf)=0
#pragma unroll
        for (int off = 1; off < 16; off <<= 1) ts += __shfl_xor(ts, off);
        const float corr = (mrow[j] == -INFINITY) ? 0.f : __expf(mrow[j] - mn);
        lrow[j] = lrow[j] * corr + ts;
        mrow[j] = mn;
      }
    }
  }

  float linv[4];
#pragma unroll
  for (int j = 0; j < 4; ++j) linv[j] = (lrow[j] > 0.f) ? 1.f / lrow[j] : 0.f;

  f32x4 cacc[4] = {};

  // ---- pass 2: write normalized attn + accumulate ctx ----
  for (int kt = 0; kt < S_LEN; kt += 64) {
    __syncthreads();
    {
      const unsigned short* srck = kb + (size_t)(kt + sk) * D_MID + head * D_HEAD + sc;
      *(uint4*)&Kt[sk][sc] = *(const uint4*)srck;
      *(uint4*)&Kt[sk][sc + 8] = *(const uint4*)(srck + 8);
      const unsigned short* srcv = vbt + (size_t)(head * D_HEAD + sk) * S_LEN + kt + sc;
      *(uint4*)&Vt[sk][sc] = *(const uint4*)srcv;
      *(uint4*)&Vt[sk][sc + 8] = *(const uint4*)(srcv + 8);
    }
    __syncthreads();

    f32x4 sacc[4];
#pragma unroll
    for (int a = 0; a < 4; ++a) {
      bf16x8 b0 = *(const bf16x8*)&Kt[a * 16 + l15][lhi * 8];
      bf16x8 b1 = *(const bf16x8*)&Kt[a * 16 + l15][32 + lhi * 8];
      f32x4 t = {0.f, 0.f, 0.f, 0.f};
      t = MFMA16(aq[0], b0, t);
      t = MFMA16(aq[1], b1, t);
      sacc[a] = t;
    }

#pragma unroll
    for (int j = 0; j < 4; ++j) {
      const int qg = q0 + w * 16 + lhi * 4 + j;
#pragma unroll
      for (int a = 0; a < 4; ++a) {
        const int kg = kt + a * 16 + l15;
        const bool mk = m32 ? (mi[(size_t)qg * S_LEN + kg] != 0)
                            : (m8[(size_t)qg * S_LEN + kg] != 0);
        float p = 0.f;
        if (!mk && mrow[j] > -INFINITY)
          p = __expf(sacc[a][j] * 0.125f - mrow[j]) * linv[j];
        attn_out[(size_t)head * S_LEN * S_LEN + (size_t)qg * S_LEN + kg] = p;
        Pl[w][lhi * 4 + j][a * 16 + l15] = f2bf(p);
      }
    }

    // wave-local LDS roundtrip: C-layout -> A-fragment layout (in-order DS pipe)
    bf16x8 pa0 = *(const bf16x8*)&Pl[w][l15][lhi * 8];
    bf16x8 pa1 = *(const bf16x8*)&Pl[w][l15][32 + lhi * 8];
#pragma unroll
    for (int n = 0; n < 4; ++n) {
      bf16x8 v0 = *(const bf16x8*)&Vt[n * 16 + l15][lhi * 8];
      bf16x8 v1 = *(const bf16x8*)&Vt[n * 16 + l15][32 + lhi * 8];
      cacc[n] = MFMA16(pa0, v0, cacc[n]);
      cacc[n] = MFMA16(pa1, v1, cacc[n]);
    }
  }

#pragma unroll
  for (int n = 0; n < 4; ++n)
#pragma unroll
    for (int j = 0; j < 4; ++j) {
      const int qg = q0 + w * 16 + lhi * 4 + j;
      const int col = head * D_HEAD + n * 16 + l15;
      const float cv = cacc[n][j];
      ctx2_out[(size_t)qg * D_MID + col] = cv;
      ctxb[(size_t)qg * D_MID + col] = f2bf(cv);
    }
}

// ---------------------------------------------------------------------------
// Row LayerNorm: 1 block per row of 1024
// ---------------------------------------------------------------------------
__global__ __launch_bounds__(256) void layernorm_k(
    const float* __restrict__ x, const float* __restrict__ gamma,
    const float* __restrict__ beta, float* __restrict__ out) {
  const int row = blockIdx.x;
  const int tid = threadIdx.x;
  float4 v = ((const float4*)(x + (size_t)row * D_MID))[tid];
  float s = v.x + v.y + v.z + v.w;
  float s2 = v.x * v.x + v.y * v.y + v.z * v.z + v.w * v.w;
#pragma unroll
  for (int off = 1; off < 64; off <<= 1) {
    s += __shfl_xor(s, off);
    s2 += __shfl_xor(s2, off);
  }
  __shared__ float ps[4], ps2[4];
  const int w = tid >> 6;
  if ((tid & 63) == 0) { ps[w] = s; ps2[w] = s2; }
  __syncthreads();
  s = ps[0] + ps[1] + ps[2] + ps[3];
  s2 = ps2[0] + ps2[1] + ps2[2] + ps2[3];
  const float mu = s * (1.0f / D_MID);
  const float var = s2 * (1.0f / D_MID) - mu * mu;
  const float inv = rsqrtf(var + 1e-5f);
  float4 g = ((const float4*)gamma)[tid];
  float4 b = ((const float4*)beta)[tid];
  float4 o;
  o.x = (v.x - mu) * inv * g.x + b.x;
  o.y = (v.y - mu) * inv * g.y + b.y;
  o.z = (v.z - mu) * inv * g.z + b.z;
  o.w = (v.w - mu) * inv * g.w + b.w;
  ((float4*)(out + (size_t)row * D_MID))[tid] = o;
}

// ---------------------------------------------------------------------------
extern "C" void kernel_launch(void* const* d_in, const int* in_sizes, int n_in,
                              void* d_out, int out_size, void* d_ws, size_t ws_size,
                              hipStream_t stream) {
  (void)in_sizes; (void)n_in; (void)out_size;
  const float* Q = (const float*)d_in[0];
  const float* K = (const float*)d_in[1];
  const float* V = (const float*)d_in[2];
  const void* mask = d_in[3];
  const float* wq = (const float*)d_in[4];
  const float* bq = (const float*)d_in[5];
  const float* wk = (const float*)d_in[6];
  const float* bk = (const float*)d_in[7];
  const float* wv = (const float*)d_in[8];
  const float* bv = (const float*)d_in[9];
  const float* wo = (const float*)d_in[10];
  const float* bo = (const float*)d_in[11];
  const float* gamma = (const float*)d_in[12];
  const float* beta = (const float*)d_in[13];

  float* out = (float*)d_out;                       // (1,2048,1024)
  float* attn = out + (size_t)S_LEN * D_MID;        // (1,16,2048,2048)
  float* ctx2 = attn + (size_t)N_HEADS * S_LEN * S_LEN;  // (2048,1,1024)

  unsigned char* ws = (unsigned char*)d_ws;         // needs 28 MB
  unsigned short* qb = (unsigned short*)(ws);
  unsigned short* kbuf = (unsigned short*)(ws + (size_t)(4 << 20));
  unsigned short* vbuf = (unsigned short*)(ws + (size_t)(8 << 20));
  unsigned short* vbt = (unsigned short*)(ws + (size_t)(12 << 20));
  unsigned short* ctxb = (unsigned short*)(ws + (size_t)(16 << 20));
  float* preLN = (float*)(ws + (size_t)(20 << 20));

  ProjParams pp;
  pp.A[0] = Q;  pp.W[0] = wq; pp.B[0] = bq; pp.O[0] = qb;
  pp.A[1] = K;  pp.W[1] = wk; pp.B[1] = bk; pp.O[1] = kbuf;
  pp.A[2] = V;  pp.W[2] = wv; pp.B[2] = bv; pp.O[2] = vbuf;

  gemm_proj<<<dim3(D_MID / 128, S_LEN / 128, 3), 256, 0, stream>>>(pp);
  transpose_to_vbt<<<dim3(S_LEN / 64, D_MID / 64), 256, 0, stream>>>(vbuf, vbt);
  attn_kernel<<<dim3(N_HEADS, S_LEN / 64), 256, 0, stream>>>(
      qb, kbuf, vbt, mask, attn, ctx2, ctxb);
  gemm_out<<<dim3(D_MID / 128, S_LEN / 128), 256, 0, stream>>>(
      ctxb, wo, bo, Q, preLN);
  layernorm_k<<<S_LEN, 256, 0, stream>>>(preLN, gamma, beta, out);
}